// Round 6
// baseline (545.860 us; speedup 1.0000x reference)
//
#include <hip/hip_runtime.h>
#include <hip/hip_bf16.h>

typedef __attribute__((ext_vector_type(8))) short short8;
typedef __attribute__((ext_vector_type(4))) float f32x4;

#define D_IN   4096
#define M_TOT  8192    // B*S = 4*2048
#define N_TOT  4096
#define BM     256
#define BN     128
#define BK     64
#define NT     (D_IN / BK)     // 64 K-steps
#define SLOT_SH 24576          // shorts per ring slot: A 256x64 (16384) + B 128x64 (8192) = 48 KiB
#define BOFF_B  16384

// ---------- helpers ----------
__device__ __forceinline__ unsigned short f2bf(float f) {
  union { float f; unsigned int u; } v; v.f = f;
  unsigned int r = v.u + 0x7fffu + ((v.u >> 16) & 1u);   // round-nearest-even
  return (unsigned short)(r >> 16);
}

__device__ __forceinline__ void async16(const void* gptr, void* lptr) {
  __builtin_amdgcn_global_load_lds(
      (const __attribute__((address_space(1))) void*)gptr,
      (__attribute__((address_space(3))) void*)lptr, 16, 0, 0);
}

#define VMCNT(n) asm volatile("s_waitcnt vmcnt(" #n ")" ::: "memory")
#define LGKMC(n) asm volatile("s_waitcnt lgkmcnt(" #n ")" ::: "memory")
#define SBAR()   __builtin_amdgcn_s_barrier()
#define SCHED0() __builtin_amdgcn_sched_barrier(0)

// ---------- kernel 1: z = bf16(x * golay), 4 elems/thread, fully coalesced ----------
__global__ __launch_bounds__(256) void prep_x_kernel(const float* __restrict__ x,
                                                     const float* __restrict__ golay,
                                                     unsigned short* __restrict__ z) {
  size_t i = ((size_t)blockIdx.x * 256 + threadIdx.x) * 4;
  float4 v = *(const float4*)(x + i);
  float4 g = *(const float4*)(golay + (i & (D_IN - 1)));
  union { unsigned short u[4]; uint2 v; } o;
  o.u[0] = f2bf(v.x * g.x);
  o.u[1] = f2bf(v.y * g.y);
  o.u[2] = f2bf(v.z * g.z);
  o.u[3] = f2bf(v.w * g.w);
  *(uint2*)(z + i) = o.v;
}

// ---------- kernel 2: Wt[o,:] = bf16(H * W[o,:]) — 3-pass register-blocked FWHT ----------
__device__ __forceinline__ void butterfly16(float v[16]) {
  #pragma unroll
  for (int s = 0; s < 4; ++s) {
    const int h = 1 << s;
    #pragma unroll
    for (int p = 0; p < 8; ++p) {
      const int i = ((p >> s) << (s + 1)) | (p & (h - 1));
      const int j = i | h;
      float a = v[i], b = v[j];
      v[i] = a + b;
      v[j] = a - b;
    }
  }
}

__global__ __launch_bounds__(256) void fwht_w_kernel(const float* __restrict__ W,
                                                     unsigned short* __restrict__ Wt) {
  __shared__ float lds[D_IN];
  const int o = blockIdx.x;
  const int tid = threadIdx.x;
  const int tHi = tid >> 4, tLo = tid & 15;
  float v[16];

  { // pass 1: load 16 consecutive (digit i0 varies), butterfly bits 0-3
    const float4* src = (const float4*)(W + (size_t)o * D_IN + tid * 16);
    #pragma unroll
    for (int q = 0; q < 4; ++q) {
      float4 t = src[q];
      v[q * 4 + 0] = t.x; v[q * 4 + 1] = t.y; v[q * 4 + 2] = t.z; v[q * 4 + 3] = t.w;
    }
  }
  butterfly16(v);
  // scatter perm(i) = i0*256 + i2*16 + i1  (thread holds i2=tHi, i1=tLo, i0=j)
  #pragma unroll
  for (int j = 0; j < 16; ++j) lds[j * 256 + tHi * 16 + tLo] = v[j];
  __syncthreads();

  { // pass 2: read consecutive (now i1 varies), butterfly bits 4-7
    const float4* src = (const float4*)(lds + tid * 16);
    #pragma unroll
    for (int q = 0; q < 4; ++q) {
      float4 t = src[q];
      v[q * 4 + 0] = t.x; v[q * 4 + 1] = t.y; v[q * 4 + 2] = t.z; v[q * 4 + 3] = t.w;
    }
  }
  butterfly16(v);
  __syncthreads();
  #pragma unroll
  for (int j = 0; j < 16; ++j) lds[j * 256 + tHi * 16 + tLo] = v[j];
  __syncthreads();

  { // pass 3: read consecutive (now i2 varies), butterfly bits 8-11
    const float4* src = (const float4*)(lds + tid * 16);
    #pragma unroll
    for (int q = 0; q < 4; ++q) {
      float4 t = src[q];
      v[q * 4 + 0] = t.x; v[q * 4 + 1] = t.y; v[q * 4 + 2] = t.z; v[q * 4 + 3] = t.w;
    }
  }
  butterfly16(v);
  unsigned short* dst = Wt + (size_t)o * D_IN;
  #pragma unroll
  for (int j = 0; j < 16; ++j)
    dst[j * 256 + tid] = f2bf(v[j] * 0.015625f);   // (1/sqrt2)^12 = 2^-6
}

// ---------- kernel 3: C = Z * Wt^T + bias, 256x128 tile, BK=64, 3-slot ring ----------
__global__ __launch_bounds__(512, 2) void gemm_bt_kernel(
    const unsigned short* __restrict__ Z,    // [M_TOT][D_IN] bf16 bits
    const unsigned short* __restrict__ Wt,   // [N_TOT][D_IN] bf16 bits
    const float* __restrict__ bias,          // [N_TOT]
    float* __restrict__ C) {                 // [M_TOT][N_TOT]
  extern __shared__ unsigned short lds[];    // 3 slots x 24576 shorts = 144 KiB

  // XCD-aware swizzle (grid = 1024, 1024 % 8 == 0)
  const int cpx = (int)gridDim.x >> 3;
  const int wg  = ((int)blockIdx.x & 7) * cpx + ((int)blockIdx.x >> 3);
  const int NTN = N_TOT / BN;              // 32
  const int bm0 = (wg / NTN) * BM;
  const int bn0 = (wg % NTN) * BN;

  const int tid = (int)threadIdx.x;
  const int ln  = tid & 63;
  const int w   = tid >> 6;                // wave 0..7
  const int lr  = ln & 15;
  const int ck  = ln >> 4;                 // k-group 0..3
  const int wr  = w >> 1;                  // 0..3 -> 64-row panel of A
  const int wc  = w & 1;                   // 0..1 -> 64-col panel of B

  // read-side chunk swizzle (both-sides involution, 128B rows, 3-bit XOR: round-2-proven 0-conflict)
  const int koff0 = ((ck     ) ^ (lr & 7)) * 8;   // kk=0 16B chunk (shorts offset)
  const int koff1 = ((4 | ck ) ^ (lr & 7)) * 8;   // kk=1

  // stage geometry: row = l*64 + (tid>>3), chunk c8 = tid&7; LDS dst linear in tid (DMA-safe)
  const int srow = tid >> 3;
  const int sc8  = tid & 7;
  const int sgc  = sc8 ^ (srow & 7);       // pre-swizzled global source chunk

  f32x4 acc[4][4] = {};

  #define STAGE(so, tt)                                                              \
    { _Pragma("unroll")                                                              \
      for (int l = 0; l < 4; ++l) {                                                  \
        const int row = l * 64 + srow;                                               \
        async16(Z + (size_t)(bm0 + row) * D_IN + (tt) * 64 + sgc * 8,                \
                lds + (so) + row * 64 + sc8 * 8);                                    \
      }                                                                              \
      _Pragma("unroll")                                                              \
      for (int l = 0; l < 2; ++l) {                                                  \
        const int row = l * 64 + srow;                                               \
        async16(Wt + (size_t)(bn0 + row) * D_IN + (tt) * 64 + sgc * 8,               \
                lds + (so) + BOFF_B + row * 64 + sc8 * 8);                           \
      } }

  #define COMPUTE(so)                                                                \
    { short8 a[4][2], b[4][2];                                                       \
      _Pragma("unroll")                                                              \
      for (int f = 0; f < 4; ++f) {                                                  \
        const int row = wr * 64 + f * 16 + lr;                                       \
        a[f][0] = *(const short8*)(lds + (so) + row * 64 + koff0);                   \
        a[f][1] = *(const short8*)(lds + (so) + row * 64 + koff1);                   \
      }                                                                              \
      _Pragma("unroll")                                                              \
      for (int n = 0; n < 4; ++n) {                                                  \
        const int row = wc * 64 + n * 16 + lr;                                       \
        b[n][0] = *(const short8*)(lds + (so) + BOFF_B + row * 64 + koff0);          \
        b[n][1] = *(const short8*)(lds + (so) + BOFF_B + row * 64 + koff1);          \
      }                                                                              \
      __builtin_amdgcn_s_setprio(1);                                                 \
      _Pragma("unroll")                                                              \
      for (int kk = 0; kk < 2; ++kk)                                                 \
        { _Pragma("unroll")                                                          \
          for (int f = 0; f < 4; ++f)                                                \
            { _Pragma("unroll")                                                      \
              for (int n = 0; n < 4; ++n)                                            \
                acc[f][n] = __builtin_amdgcn_mfma_f32_16x16x32_bf16(                 \
                    a[f][kk], b[n][kk], acc[f][n], 0, 0, 0); } }                     \
      __builtin_amdgcn_s_setprio(0); }

  // prologue: stage tiles 0,1,2 into slots 0,1,2; require tile 0 landed (12 = tiles 1,2 in flight)
  STAGE(0, 0)
  STAGE(SLOT_SH, 1)
  STAGE(2 * SLOT_SH, 2)
  VMCNT(12); SBAR();

  // main loop: compute t from slot(t); sync; stage t+3 into the same slot (t+3 ≡ t mod 3)
  int so = 0;
  for (int t = 0; t <= NT - 4; ++t) {
    COMPUTE(so)
    SCHED0(); LGKMC(0); VMCNT(6); SBAR();
    STAGE(so, t + 3)
    so = (so == 2 * SLOT_SH) ? 0 : so + SLOT_SH;
  }
  // epilogue: tile NT-3 landed via last loop sync (for ALL waves).
  // Each further drain must be vmcnt -> s_barrier before any wave reads:
  // vmcnt is per-wave; only the barrier makes other waves' DMA landing visible.
  COMPUTE(so)
  so = (so == 2 * SLOT_SH) ? 0 : so + SLOT_SH;
  VMCNT(6); SBAR();         // tile NT-2 landed, all waves
  COMPUTE(so)
  so = (so == 2 * SLOT_SH) ? 0 : so + SLOT_SH;
  VMCNT(0); SBAR();         // tile NT-1 landed, all waves
  COMPUTE(so)

  // epilogue write: C/D layout col = lane&15, row = (lane>>4)*4 + reg
  const int cm = bm0 + wr * 64;
  const int cn = bn0 + wc * 64 + lr;
  #pragma unroll
  for (int n = 0; n < 4; ++n) {
    const float bv = bias[cn + n * 16];
    #pragma unroll
    for (int f = 0; f < 4; ++f) {
      #pragma unroll
      for (int r = 0; r < 4; ++r) {
        C[(size_t)(cm + f * 16 + ck * 4 + r) * N_TOT + cn + n * 16] = acc[f][n][r] + bv;
      }
    }
  }
}

extern "C" void kernel_launch(void* const* d_in, const int* in_sizes, int n_in,
                              void* d_out, int out_size, void* d_ws, size_t ws_size,
                              hipStream_t stream) {
  const float* x     = (const float*)d_in[0];   // [4,2048,4096] fp32
  const float* golay = (const float*)d_in[1];   // [4096] fp32 (+-1)
  const float* W     = (const float*)d_in[2];   // [4096,4096] fp32
  const float* bias  = (const float*)d_in[3];   // [4096] fp32
  float* out         = (float*)d_out;           // [4,2048,4096] fp32

  unsigned short* z  = (unsigned short*)d_ws;                                     // 64 MiB bf16
  unsigned short* wt = (unsigned short*)((char*)d_ws + (size_t)M_TOT * D_IN * 2); // 32 MiB bf16

  prep_x_kernel<<<(M_TOT * D_IN) / (256 * 4), 256, 0, stream>>>(x, golay, z);
  fwht_w_kernel<<<N_TOT, 256, 0, stream>>>(W, wt);
  gemm_bt_kernel<<<(M_TOT / BM) * (N_TOT / BN), 512, 3 * SLOT_SH * 2, stream>>>(z, wt, bias, out);
}